// Round 9
// baseline (14.409 us; speedup 1.0000x reference)
//
#include <hip/hip_runtime.h>

#define HH 1024
#define WW 1024
#define NA 64
#define NBLK1 256          // k1: 4 rows per block, 1024 threads, 4 px/thread
#define NBLK2 128          // k2: 1024 threads, 8 px/thread

// ws layout: float2 part[NBLK1]  (x = sum field^2, y = sum upd^2)

// ------------- Kernel 1: blend + unscaled out + norm partials --------------
__global__ __launch_bounds__(1024) void frp_fused(
    const float4* __restrict__ field,
    const float4* __restrict__ signal,
    const int*   __restrict__ apos,       // [NA][2]
    const float* __restrict__ astr,       // [NA]
    const float* __restrict__ p_is,
    const float* __restrict__ p_gr,
    const float* __restrict__ p_lr,
    float4* __restrict__ out,
    float2* __restrict__ part)
{
    __shared__ int   s_pj[4][NA];
    __shared__ int   s_rad[4][NA];
    __shared__ int   s_di2[4][NA];
    __shared__ float s_coef[4][NA];
    __shared__ float s_inv[4][NA];
    __shared__ int   s_nact[4];
    __shared__ float s_part[2][16];

    const float lr = *p_lr;
    const float gr = *p_gr;
    const float is = *p_is;

    const int t    = threadIdx.x;
    const int row0 = blockIdx.x * 4;

    // ---- waves 0..3: wave w compacts active attractors for row0+w ----
    if (t < 256) {
        const int w    = t >> 6;          // wave index = row within block
        const int lane = t & 63;          // attractor index
        float s  = astr[lane];
        int   pi = apos[2 * lane + 0];
        int   pj = apos[2 * lane + 1];
        int   r  = (int)floorf(5.0f * s);
        int   di = (row0 + w) - pi;
        bool active = (di >= -r && di <= r);
        unsigned long long mask = __ballot(active);
        int pos = __popcll(mask & ((1ull << lane) - 1ull));
        if (active) {
            s_pj[w][pos]   = pj;
            s_rad[w][pos]  = r;
            s_di2[w][pos]  = di * di;
            s_coef[w][pos] = lr * s;
            s_inv[w][pos]  = -0.125f / (s * s);
        }
        if (lane == 0) s_nact[w] = __popcll(mask);
    }
    __syncthreads();

    // 256 threads per row: rr = t>>8, 4 consecutive px per thread
    const int rr   = t >> 8;
    const int tt   = t & 255;
    const int row  = row0 + rr;
    const int col0 = tt << 2;
    const int n    = s_nact[rr];

    float c0 = 0.f, c1 = 0.f, c2 = 0.f, c3 = 0.f;
    for (int k = 0; k < n; ++k) {         // ~1.1 iterations on average
        int   pj  = s_pj[rr][k];
        int   r   = s_rad[rr][k];
        int   di2 = s_di2[rr][k];
        float cf  = s_coef[rr][k];
        float iv  = s_inv[rr][k];
        int dj = col0 - pj;
        if (dj >= -r && dj <= r) c0 += cf * __expf(iv * (float)(di2 + dj * dj));
        int d1 = dj + 1;
        if (d1 >= -r && d1 <= r) c1 += cf * __expf(iv * (float)(di2 + d1 * d1));
        int d2 = dj + 2;
        if (d2 >= -r && d2 <= r) c2 += cf * __expf(iv * (float)(di2 + d2 * d2));
        int d3 = dj + 3;
        if (d3 >= -r && d3 <= r) c3 += cf * __expf(iv * (float)(di2 + d3 * d3));
    }

    const int idx = row * (WW / 4) + tt;
    float4 f  = field[idx];
    float4 sg = signal[idx];

    float a0 = is / (1.0f + __expf(-(gr + c0)));
    float a1 = is / (1.0f + __expf(-(gr + c1)));
    float a2 = is / (1.0f + __expf(-(gr + c2)));
    float a3 = is / (1.0f + __expf(-(gr + c3)));

    float4 u;
    u.x = f.x + (sg.x - f.x) * a0;
    u.y = f.y + (sg.y - f.y) * a1;
    u.z = f.z + (sg.z - f.z) * a2;
    u.w = f.w + (sg.w - f.w) * a3;
    out[idx] = u;

    float sf = f.x * f.x + f.y * f.y + f.z * f.z + f.w * f.w;
    float su = u.x * u.x + u.y * u.y + u.z * u.z + u.w * u.w;
#pragma unroll
    for (int off = 32; off > 0; off >>= 1) {
        sf += __shfl_down(sf, off, 64);
        su += __shfl_down(su, off, 64);
    }
    const int wave = t >> 6;              // 16 waves
    if ((t & 63) == 0) {
        s_part[0][wave] = sf;
        s_part[1][wave] = su;
    }
    __syncthreads();
    if (t == 0) {
        float tf = 0.f, tu = 0.f;
#pragma unroll
        for (int q = 0; q < 16; ++q) { tf += s_part[0][q]; tu += s_part[1][q]; }
        part[blockIdx.x] = make_float2(tf, tu);
    }
}

// ---- Kernel 2: reduce 256 partials (redundantly) and scale out in place ----
__global__ __launch_bounds__(1024) void frp_scale(
    float4* __restrict__ out,
    const float2* __restrict__ part)
{
    __shared__ double sp[2][16];
    __shared__ float  s_scale;
    const int t = threadIdx.x;

    // 256 float2 = 128 float4: threads 0..127 load one each
    double df = 0.0, du = 0.0;
    if (t < 128) {
        const float4* p4 = (const float4*)part;  // (f0,u0,f1,u1)
        float4 v = p4[t];
        df = (double)v.x + (double)v.z;
        du = (double)v.y + (double)v.w;
    }

    // issue out loads early (independent of the reduce)
    const int idx = blockIdx.x * 2048 + (t << 1);  // 2048 float4 per block
    float4 o0 = out[idx];
    float4 o1 = out[idx + 1];

#pragma unroll
    for (int off = 32; off > 0; off >>= 1) {
        df += __shfl_down(df, off, 64);
        du += __shfl_down(du, off, 64);
    }
    const int wave = t >> 6;
    if ((t & 63) == 0) { sp[0][wave] = df; sp[1][wave] = du; }
    __syncthreads();
    if (t == 0) {
        double tf = 0.0, tu = 0.0;
#pragma unroll
        for (int q = 0; q < 16; ++q) { tf += sp[0][q]; tu += sp[1][q]; }
        s_scale = (tu > 0.0) ? (float)sqrt(tf / tu) : 1.0f;
    }
    __syncthreads();

    const float s = s_scale;
    o0.x *= s; o0.y *= s; o0.z *= s; o0.w *= s;
    o1.x *= s; o1.y *= s; o1.z *= s; o1.w *= s;
    out[idx]     = o0;
    out[idx + 1] = o1;
}

extern "C" void kernel_launch(void* const* d_in, const int* in_sizes, int n_in,
                              void* d_out, int out_size, void* d_ws, size_t ws_size,
                              hipStream_t stream) {
    const float4* field  = (const float4*)d_in[0];
    const float4* signal = (const float4*)d_in[1];
    const int*    apos   = (const int*)d_in[2];
    const float*  astr   = (const float*)d_in[3];
    const float*  p_is   = (const float*)d_in[4];
    const float*  p_gr   = (const float*)d_in[5];
    const float*  p_lr   = (const float*)d_in[6];

    float2* part = (float2*)d_ws;

    frp_fused<<<NBLK1, 1024, 0, stream>>>(
        field, signal, apos, astr, p_is, p_gr, p_lr,
        (float4*)d_out, part);

    frp_scale<<<NBLK2, 1024, 0, stream>>>(
        (float4*)d_out, part);
}